// Round 8
// baseline (26.282 us; speedup 1.0000x reference)
//
#include <hip/hip_runtime.h>
#include <math.h>

#define NQ 10

typedef float v2f __attribute__((ext_vector_type(2)));

static __device__ __forceinline__ v2f mk2(float a, float b) { v2f r; r.x = a; r.y = b; return r; }
static __device__ __forceinline__ v2f sp2(float a)          { v2f r; r.x = a; r.y = a; return r; }
static __device__ __forceinline__ v2f pkfma(v2f a, v2f b, v2f c) { return __builtin_elementwise_fma(a, b, c); }

// xor-mask lane exchange. Masks 1,2,4,8: DPP (VALU pipe). 16: ds_swizzle. 32: bpermute.
// row_shl:N -> lane i receives lane i+N; row_shr:N -> lane i receives lane i-N.
template<int MSK>
static __device__ __forceinline__ float lxor(float v) {
    if constexpr (MSK == 1) {        // quad_perm [1,0,3,2]
        const int s = __float_as_int(v);
        return __int_as_float(__builtin_amdgcn_update_dpp(s, s, 0xB1, 0xF, 0xF, false));
    } else if constexpr (MSK == 2) { // quad_perm [2,3,0,1]
        const int s = __float_as_int(v);
        return __int_as_float(__builtin_amdgcn_update_dpp(s, s, 0x4E, 0xF, 0xF, false));
    } else if constexpr (MSK == 4) {
        // banks 0,2 (bit2=0) need lane+4 -> row_shl:4 ; banks 1,3 (bit2=1) need lane-4 -> row_shr:4
        const int s = __float_as_int(v);
        int t = __builtin_amdgcn_update_dpp(s, s, 0x104, 0xF, 0x5, false); // row_shl:4 into banks 0,2
        t     = __builtin_amdgcn_update_dpp(t, s, 0x114, 0xF, 0xA, false); // row_shr:4 into banks 1,3
        return __int_as_float(t);
    } else if constexpr (MSK == 8) { // row_ror:8 == xor8 within a 16-lane row
        const int s = __float_as_int(v);
        return __int_as_float(__builtin_amdgcn_update_dpp(s, s, 0x128, 0xF, 0xF, false));
    } else if constexpr (MSK == 16) {
        return __int_as_float(__builtin_amdgcn_ds_swizzle(__float_as_int(v), 0x401F));
    } else {
        return __shfl_xor(v, 32, 64);
    }
}
template<int MSK>
static __device__ __forceinline__ v2f lxor2(v2f v) { return mk2(lxor<MSK>(v.x), lxor<MSK>(v.y)); }

// TWO waves per batch element (128-thread block = 1 element). 1024 amplitudes:
//   k = (w << 9) | (p << 7) | (e << 6) | lane   (w = wave bit, p = v2f pair 0..3, e = component)
//   wire 0 (bit 9): cross-wave via dbuf LDS exchange, 1 barrier/layer
//   wires 1,2 (p bits 1,0): packed register-pair gates
//   wire 3 (e): intra-v2f, coefficient-swapped pkfma
//   wires 4..9 (lane bits 5..0): lxor exchange gates
// Final CZ dropped (|psi|^2 invariant). launch_bounds(128,4): 4 waves/SIMD, VGPR cap 128.
__global__ __launch_bounds__(128, 4) void qlayer_kernel(
    const float* __restrict__ x,    // [B,10]
    const float* __restrict__ w1,   // [3,1,10,3]
    const float* __restrict__ w2,   // [1,10,3]
    float* __restrict__ out)        // [B,10]
{
    __shared__ __align__(16) float g[40 * 8];  // 40 gate matrices {M00,M01,M10,M11}(r,i)
    __shared__ v2f   ex[2][2][8][64];          // [dbuf][w][sr0..3,si0..3][lane], 16 KB
    __shared__ float red[2][NQ];

    const int t    = threadIdx.x;   // 0..127
    const int lane = t & 63;
    const int w    = t >> 6;        // 0 or 1
    const int b    = blockIdx.x;

    if (t < 40) {
        const int L = t / 10, j = t - L * 10;
        const float* wb = (L < 3) ? (w1 + L * 30 + j * 3) : (w2 + j * 3);
        const float phi = wb[0], th = wb[1], om = wb[2];
        float ct, st, epr, epi, emr, emi;
        __sincosf(0.5f * th, &st, &ct);
        __sincosf(-0.5f * (phi + om), &epi, &epr);
        __sincosf(-0.5f * (phi - om), &emi, &emr);
        float* gp = &g[t * 8];
        gp[0] =  epr * ct; gp[1] =  epi * ct;        // M00
        gp[2] = -emr * st; gp[3] =  emi * st;        // M01 = -conj(em)*s
        gp[4] =  emr * st; gp[5] =  emi * st;        // M10
        gp[6] =  epr * ct; gp[7] = -epi * ct;        // M11 = conj(ep)*c
    }

    // ---- per-lane prologue ----
    float xv[NQ];
#pragma unroll
    for (int j = 0; j < NQ; ++j) xv[j] = x[b * NQ + j];
    float S = 0.f;
#pragma unroll
    for (int j = 0; j < NQ; ++j) S += xv[j];
    float Tlo = 0.f;
#pragma unroll
    for (int p = 0; p < 6; ++p) Tlo += ((lane >> p) & 1) ? xv[9 - p] : 0.f;
    const float base = -0.5f * S + Tlo + (w ? xv[0] : 0.f);   // bit 9 = wire 0

    // CZ sign per m (k = w<<9 | m<<6 | lane, m = p<<1|e, 3 bits)
    float czm[8];
#pragma unroll
    for (int m = 0; m < 8; ++m) {
        const int k  = (w << 9) | (m << 6) | lane;
        const int kr = ((k << 1) | (k >> 9)) & 1023;
        czm[m] = (__popc(k & kr) & 1) ? -1.f : 1.f;
    }

    // phase diagonal over 3 m-bits via Gray chain: 4 sincos + 7 cmul
    // m bit0 = e -> xv[3]; bit1 = p bit0 -> xv[2]; bit2 = p bit1 -> xv[1]
    float frq[3], fiq[3];
#pragma unroll
    for (int q = 0; q < 3; ++q) __sincosf(xv[3 - q], &fiq[q], &frq[q]);
    float dmr[8], dmi[8];
    __sincosf(base, &dmi[0], &dmr[0]);
#pragma unroll
    for (int m = 1; m < 8; ++m) {
        const int q  = (m & 1) ? 0 : (m & 2) ? 1 : 2;
        const int pm = m & (m - 1);
        dmr[m] = dmr[pm] * frq[q] - dmi[pm] * fiq[q];
        dmi[m] = dmr[pm] * fiq[q] + dmi[pm] * frq[q];
    }
    v2f dr[4], di[4];
#pragma unroll
    for (int p = 0; p < 4; ++p) {
        dr[p] = mk2(dmr[2 * p] * czm[2 * p], dmr[2 * p + 1] * czm[2 * p + 1]);
        di[p] = mk2(dmi[2 * p] * czm[2 * p], dmi[2 * p + 1] * czm[2 * p + 1]);
    }

    v2f sr[4], si[4];
#pragma unroll
    for (int p = 0; p < 4; ++p) { sr[p] = sp2(0.f); si[p] = sp2(0.f); }
    if (t == 0) sr[0].x = 1.f;      // k=0: w=0, lane=0, p=e=0

    __syncthreads();   // gate table ready

#define LANE_WIRE(J, MSK)                                                                        \
    {                                                                                            \
        const float4 A  = *(const float4*)(gl + (J) * 8);                                        \
        const float4 Bq = *(const float4*)(gl + (J) * 8 + 4);                                    \
        const bool hi  = (lane >> (9 - (J))) & 1;                                                \
        const v2f Ar  = sp2(hi ?  Bq.z :  A.x);                                                  \
        const v2f Ai  = sp2(hi ?  Bq.w :  A.y);                                                  \
        const v2f nAi = -Ai;                                                                     \
        const v2f Br  = sp2(hi ?  Bq.x :  A.z);                                                  \
        const v2f Bi  = sp2(hi ?  Bq.y :  A.w);                                                  \
        const v2f nBi = -Bi;                                                                     \
        _Pragma("unroll")                                                                        \
        for (int p = 0; p < 4; ++p) {                                                            \
            const v2f qr = lxor2<MSK>(sr[p]);                                                    \
            const v2f qi = lxor2<MSK>(si[p]);                                                    \
            v2f tr, ti;                                                                          \
            tr = pkfma(nBi, qi, Br * qr); tr = pkfma(nAi, si[p], tr); tr = pkfma(Ar, sr[p], tr); \
            ti = pkfma(Bi,  qr, Br * qi); ti = pkfma(Ai,  sr[p], ti); ti = pkfma(Ar, si[p], ti); \
            sr[p] = tr; si[p] = ti;                                                              \
        }                                                                                        \
    }

#pragma unroll 1
    for (int L = 0; L < 4; ++L) {
        const float* gl = g + L * 80;

        LANE_WIRE(4, 32)
        LANE_WIRE(5, 16)
        LANE_WIRE(6, 8)
        LANE_WIRE(7, 4)
        LANE_WIRE(8, 2)
        LANE_WIRE(9, 1)

        // p-wires: wire 1 (p bit 1: pairs 0-2,1-3), wire 2 (p bit 0: pairs 0-1,2-3)
#pragma unroll
        for (int jj = 0; jj < 2; ++jj) {
            const int j  = 1 + jj;
            const int pb = (j == 1) ? 2 : 1;
            const float4 A  = *(const float4*)(gl + j * 8);
            const float4 Bq = *(const float4*)(gl + j * 8 + 4);
            const v2f g0 = sp2(A.x),  g1 = sp2(A.y),  g2 = sp2(A.z),  g3 = sp2(A.w);
            const v2f g4 = sp2(Bq.x), g5 = sp2(Bq.y), g6 = sp2(Bq.z), g7 = sp2(Bq.w);
#pragma unroll
            for (int p0 = 0; p0 < 4; ++p0) {
                if (p0 & pb) continue;
                const int p1 = p0 | pb;
                const v2f a0r = sr[p0], a0i = si[p0];
                const v2f a1r = sr[p1], a1i = si[p1];
                sr[p0] = pkfma(g0, a0r, pkfma(-g1, a0i, pkfma(g2, a1r, -g3 * a1i)));
                si[p0] = pkfma(g0, a0i, pkfma( g1, a0r, pkfma(g2, a1i,  g3 * a1r)));
                sr[p1] = pkfma(g4, a0r, pkfma(-g5, a0i, pkfma(g6, a1r, -g7 * a1i)));
                si[p1] = pkfma(g4, a0i, pkfma( g5, a0r, pkfma(g6, a1i,  g7 * a1r)));
            }
        }

        // e-wire (wire 3, m bit 0): coefficient-swapped packed gate
        {
            const float4 A  = *(const float4*)(gl + 3 * 8);
            const float4 Bq = *(const float4*)(gl + 3 * 8 + 4);
            const v2f CAr = mk2(A.x, Bq.z), CAi = mk2(A.y, Bq.w);   // {M00, M11}
            const v2f CBr = mk2(A.z, Bq.x), CBi = mk2(A.w, Bq.y);   // {M01, M10}
            const v2f nCAi = -CAi, nCBi = -CBi;
#pragma unroll
            for (int p = 0; p < 4; ++p) {
                const v2f swr = mk2(sr[p].y, sr[p].x);
                const v2f swi = mk2(si[p].y, si[p].x);
                v2f tr, ti;
                tr = pkfma(nCBi, swi, CBr * swr); tr = pkfma(nCAi, si[p], tr); tr = pkfma(CAr, sr[p], tr);
                ti = pkfma(CBi,  swr, CBr * swi); ti = pkfma(CAi,  sr[p], ti); ti = pkfma(CAr, si[p], ti);
                sr[p] = tr; si[p] = ti;
            }
        }

        // cross-wave wire 0 (bit 9): LDS exchange, dbuf, one barrier
        {
            const float4 A  = *(const float4*)(gl);
            const float4 Bq = *(const float4*)(gl + 4);
            const v2f Ar  = sp2(w ? Bq.z : A.x);
            const v2f Ai  = sp2(w ? Bq.w : A.y);
            const v2f nAi = -Ai;
            const v2f Br  = sp2(w ? Bq.x : A.z);
            const v2f Bi  = sp2(w ? Bq.y : A.w);
            const v2f nBi = -Bi;
            const int buf = L & 1;
#pragma unroll
            for (int p = 0; p < 4; ++p) {
                ex[buf][w][p][lane]     = sr[p];
                ex[buf][w][4 + p][lane] = si[p];
            }
            __syncthreads();
#pragma unroll
            for (int p = 0; p < 4; ++p) {
                const v2f qr = ex[buf][w ^ 1][p][lane];
                const v2f qi = ex[buf][w ^ 1][4 + p][lane];
                v2f tr, ti;
                tr = pkfma(nBi, qi, Br * qr); tr = pkfma(nAi, si[p], tr); tr = pkfma(Ar, sr[p], tr);
                ti = pkfma(Bi,  qr, Br * qi); ti = pkfma(Ai,  sr[p], ti); ti = pkfma(Ar, si[p], ti);
                sr[p] = tr; si[p] = ti;
            }
        }

        // diagonal (CZ * data-reupload) for entangling layers only
        if (L < 3) {
#pragma unroll
            for (int p = 0; p < 4; ++p) {
                const v2f tr = pkfma(sr[p], dr[p], -(si[p] * di[p]));
                si[p] = pkfma(sr[p], di[p], si[p] * dr[p]);
                sr[p] = tr;
            }
        }
    }
#undef LANE_WIRE

    // ---- <Z_j> per-wave partials ----
    float pe[4], po[4];
#pragma unroll
    for (int p = 0; p < 4; ++p) {
        const v2f pk = pkfma(sr[p], sr[p], si[p] * si[p]);
        pe[p] = pk.x + pk.y;
        po[p] = pk.x - pk.y;
    }
    float tot = 0.f, t1 = 0.f, t2 = 0.f, t3 = 0.f;
#pragma unroll
    for (int p = 0; p < 4; ++p) {
        tot += pe[p];
        t1  += (p & 2) ? -pe[p] : pe[p];   // wire 1 (p bit 1)
        t2  += (p & 1) ? -pe[p] : pe[p];   // wire 2 (p bit 0)
        t3  += po[p];                      // wire 3 (e)
    }
    v2f u = mk2(t1, t2);
    u += lxor2<1>(u); u += lxor2<2>(u); u += lxor2<4>(u);
    u += lxor2<8>(u); u += lxor2<16>(u); u += lxor2<32>(u);
    t3 += lxor<1>(t3); t3 += lxor<2>(t3); t3 += lxor<4>(t3);
    t3 += lxor<8>(t3); t3 += lxor<16>(t3); t3 += lxor<32>(t3);

    // butterfly on tot: full sum Sa (wire 0) + D_P (wire 9-P)
    float Sa = tot, T, D0, D1, D2, D3, D4, D5;
    T = lxor<1>(Sa);  D0 = Sa - T; Sa += T;
    T = lxor<2>(Sa);  D1 = Sa - T; Sa += T;
    T = lxor<4>(Sa);  D2 = Sa - T; Sa += T;
    T = lxor<8>(Sa);  D3 = Sa - T; Sa += T;
    T = lxor<16>(Sa); D4 = Sa - T; Sa += T;
    T = lxor<32>(Sa); D5 = Sa - T; Sa += T;
    D0 += lxor<2>(D0); D0 += lxor<4>(D0); D0 += lxor<8>(D0); D0 += lxor<16>(D0); D0 += lxor<32>(D0);
    D1 += lxor<4>(D1); D1 += lxor<8>(D1); D1 += lxor<16>(D1); D1 += lxor<32>(D1);
    D2 += lxor<8>(D2); D2 += lxor<16>(D2); D2 += lxor<32>(D2);
    D3 += lxor<16>(D3); D3 += lxor<32>(D3);
    D4 += lxor<32>(D4);

    if (lane == 0) {
        red[w][0] = w ? -Sa : Sa;          // wire 0 (bit 9 = w)
        red[w][1] = u.x;  red[w][2] = u.y;  red[w][3] = t3;
        red[w][4] = D5;   red[w][5] = D4;   red[w][6] = D3;
        red[w][7] = D2;   red[w][8] = D1;   red[w][9] = D0;
    }
    __syncthreads();
    if (t < NQ)
        out[b * NQ + t] = red[0][t] + red[1][t];
}

extern "C" void kernel_launch(void* const* d_in, const int* in_sizes, int n_in,
                              void* d_out, int out_size, void* d_ws, size_t ws_size,
                              hipStream_t stream) {
    const float* x  = (const float*)d_in[0];   // [B,10] f32
    const float* w1 = (const float*)d_in[1];   // [3,1,10,3] f32
    const float* w2 = (const float*)d_in[2];   // [1,10,3] f32
    float* out = (float*)d_out;                // [B,10] f32
    const int B = in_sizes[0] / NQ;            // 2048
    qlayer_kernel<<<B, 128, 0, stream>>>(x, w1, w2, out);  // 2 waves per element
}

// Round 9
// 18.045 us; speedup vs baseline: 1.4565x; 1.4565x over previous
//
#include <hip/hip_runtime.h>
#include <math.h>

#define NQ 10

typedef float v2f __attribute__((ext_vector_type(2)));

static __device__ __forceinline__ v2f mk2(float a, float b) { v2f r; r.x = a; r.y = b; return r; }
static __device__ __forceinline__ v2f sp2(float a)          { v2f r; r.x = a; r.y = a; return r; }
static __device__ __forceinline__ v2f pkfma(v2f a, v2f b, v2f c) { return __builtin_elementwise_fma(a, b, c); }

// xor-mask lane exchange. Masks 1,2,4,8: DPP (VALU pipe). 16: ds_swizzle. 32: bpermute.
// row_shl:N -> lane i receives lane i+N; row_shr:N -> lane i receives lane i-N.
template<int MSK>
static __device__ __forceinline__ float lxor(float v) {
    if constexpr (MSK == 1) {        // quad_perm [1,0,3,2]
        const int s = __float_as_int(v);
        return __int_as_float(__builtin_amdgcn_update_dpp(s, s, 0xB1, 0xF, 0xF, false));
    } else if constexpr (MSK == 2) { // quad_perm [2,3,0,1]
        const int s = __float_as_int(v);
        return __int_as_float(__builtin_amdgcn_update_dpp(s, s, 0x4E, 0xF, 0xF, false));
    } else if constexpr (MSK == 4) {
        // banks 0,2 (bit2=0) need lane+4 -> row_shl:4 ; banks 1,3 (bit2=1) need lane-4 -> row_shr:4
        const int s = __float_as_int(v);
        int t = __builtin_amdgcn_update_dpp(s, s, 0x104, 0xF, 0x5, false); // row_shl:4 into banks 0,2
        t     = __builtin_amdgcn_update_dpp(t, s, 0x114, 0xF, 0xA, false); // row_shr:4 into banks 1,3
        return __int_as_float(t);
    } else if constexpr (MSK == 8) { // row_ror:8 == xor8 within a 16-lane row
        const int s = __float_as_int(v);
        return __int_as_float(__builtin_amdgcn_update_dpp(s, s, 0x128, 0xF, 0xF, false));
    } else if constexpr (MSK == 16) {
        return __int_as_float(__builtin_amdgcn_ds_swizzle(__float_as_int(v), 0x401F));
    } else {
        return __shfl_xor(v, 32, 64);
    }
}
template<int MSK>
static __device__ __forceinline__ v2f lxor2(v2f v) { return mk2(lxor<MSK>(v.x), lxor<MSK>(v.y)); }

// One WAVE per batch element (4 per 256-thread block). k = m*64+lane, m = 2p+e.
// Circuit algebraically reduced to:  P0 (real product state = RY0|0..0>)
//   -> D1 -> RY1 -> D2 -> RY2 -> D3 -> RY3 -> |.|^2
// where D_L = CZ * diag(exp(i*ang)), ang from alpha_L[j] = omega_L[j]+x[j]+phi_{L+1}[j].
// Leading RZ(phi0) = global phase (dropped); trailing RZ(omega3)*CZ dropped (|.|^2-invariant).
// RY gates are REAL rotations: 4 pk-ops per v2f pair, coefficient = {c uniform, +-s}.
__global__ void qlayer_kernel(
    const float* __restrict__ x,    // [B,10]
    const float* __restrict__ w1,   // [3,1,10,3]
    const float* __restrict__ w2,   // [1,10,3]
    float* __restrict__ out)        // [B,10]
{
    __shared__ float ry[4 * 20];   // (c,s)(theta/2) per layer L=0..3, wire j=0..9
    __shared__ float au[3 * 10];   // omega_L[j] + phi_{L+1}[j], L=0..2

    const int t    = threadIdx.x;
    const int lane = t & 63;
    const int w    = t >> 6;
    const int b    = (blockIdx.x << 2) + w;

    if (t < 40) {
        const int L = t / 10, j = t - L * 10;
        const float th = (L < 3) ? w1[L * 30 + j * 3 + 1] : w2[j * 3 + 1];
        float c, s;
        __sincosf(0.5f * th, &s, &c);
        ry[L * 20 + j * 2 + 0] = c;
        ry[L * 20 + j * 2 + 1] = s;
    } else if (t >= 64 && t < 94) {
        const int i = t - 64, L = i / 10, j = i - L * 10;
        au[i] = w1[L * 30 + j * 3 + 2] + ((L < 2) ? w1[(L + 1) * 30 + j * 3] : w2[j * 3]);
    }

    float xv[NQ];
#pragma unroll
    for (int j = 0; j < NQ; ++j) xv[j] = x[b * NQ + j];

    // sign masks: lane-bit p set (hi half of pair) -> +s ; clear -> -s
    int msk[6];
#pragma unroll
    for (int p = 0; p < 6; ++p) msk[p] = ((lane >> p) & 1) ? 0 : 0x80000000;

    // CZ-ring sign per m (k = m<<6 | lane)
    float czm[16];
#pragma unroll
    for (int m = 0; m < 16; ++m) {
        const int k  = (m << 6) | lane;
        const int kr = ((k << 1) | (k >> 9)) & 1023;
        czm[m] = (__popc(k & kr) & 1) ? -1.f : 1.f;
    }

    __syncthreads();   // tables ready (only block barrier)

    // D build: d = cz * exp(i*ang(k)), ang(k) = -SA/2 + sum_{bits set} A[wire]
    v2f dr[8], di[8];
#define BUILD_D(IDX)                                                                   \
    {                                                                                  \
        float A[NQ];                                                                   \
        _Pragma("unroll")                                                              \
        for (int j = 0; j < NQ; ++j) A[j] = au[(IDX) * 10 + j] + xv[j];                \
        float SA = 0.f;                                                                \
        _Pragma("unroll")                                                              \
        for (int j = 0; j < NQ; ++j) SA += A[j];                                       \
        float Tl = 0.f;                                                                \
        _Pragma("unroll")                                                              \
        for (int p = 0; p < 6; ++p) Tl += ((lane >> p) & 1) ? A[9 - p] : 0.f;          \
        const float base = -0.5f * SA + Tl;                                            \
        float fr[4], fi[4];                                                            \
        _Pragma("unroll")                                                              \
        for (int q = 0; q < 4; ++q) __sincosf(A[3 - q], &fi[q], &fr[q]);               \
        float dmr[16], dmi[16];                                                        \
        __sincosf(base, &dmi[0], &dmr[0]);                                             \
        _Pragma("unroll")                                                              \
        for (int m = 1; m < 16; ++m) {                                                 \
            const int q  = (m & 1) ? 0 : (m & 2) ? 1 : (m & 4) ? 2 : 3;                \
            const int pm = m & (m - 1);                                                \
            dmr[m] = dmr[pm] * fr[q] - dmi[pm] * fi[q];                                \
            dmi[m] = dmr[pm] * fi[q] + dmi[pm] * fr[q];                                \
        }                                                                              \
        _Pragma("unroll")                                                              \
        for (int p = 0; p < 8; ++p) {                                                  \
            dr[p] = mk2(dmr[2*p] * czm[2*p], dmr[2*p+1] * czm[2*p+1]);                 \
            di[p] = mk2(dmi[2*p] * czm[2*p], dmi[2*p+1] * czm[2*p+1]);                 \
        }                                                                              \
    }

    // ---- initial product state: RY-block 0 applied to |0..0> ----
    float Plo = 1.f;
#pragma unroll
    for (int p = 0; p < 6; ++p) {       // lane bit p <-> wire 9-p
        const float cc = ry[(9 - p) * 2], ss = ry[(9 - p) * 2 + 1];
        Plo *= ((lane >> p) & 1) ? ss : cc;
    }
    float Pm[16];
    {
        const float c0 = ry[0], s0 = ry[1], c1 = ry[2], s1 = ry[3];
        const float c2 = ry[4], s2 = ry[5], c3 = ry[6], s3 = ry[7];
        float P2[2] = {c3, s3};          // m bit0 = wire 3
        float P4[4], P8[8];
#pragma unroll
        for (int m = 0; m < 4; ++m)  P4[m] = ((m >> 1) ? s2 : c2) * P2[m & 1];
#pragma unroll
        for (int m = 0; m < 8; ++m)  P8[m] = ((m >> 2) ? s1 : c1) * P4[m & 3];
#pragma unroll
        for (int m = 0; m < 16; ++m) Pm[m] = ((m >> 3) ? s0 : c0) * P8[m & 7];
    }

    BUILD_D(0)
    v2f sr[8], si[8];
#pragma unroll
    for (int p = 0; p < 8; ++p) {
        const v2f pv = sp2(Plo) * mk2(Pm[2 * p], Pm[2 * p + 1]);
        sr[p] = pv * dr[p];
        si[p] = pv * di[p];
    }

#define RY_LANE(J, MSK)                                                         \
    {                                                                           \
        const float c = rl[(J) * 2], s = rl[(J) * 2 + 1];                       \
        const float ssg = __int_as_float(__float_as_int(s) ^ msk[9 - (J)]);     \
        const v2f C = sp2(c), S = sp2(ssg);                                     \
        _Pragma("unroll")                                                       \
        for (int p = 0; p < 8; ++p) {                                           \
            const v2f qr = lxor2<MSK>(sr[p]);                                   \
            const v2f qi = lxor2<MSK>(si[p]);                                   \
            sr[p] = pkfma(C, sr[p], S * qr);                                    \
            si[p] = pkfma(C, si[p], S * qi);                                    \
        }                                                                       \
    }

#pragma unroll 1
    for (int L = 1; L <= 3; ++L) {
        const float* rl = ry + L * 20;

        RY_LANE(4, 32)
        RY_LANE(5, 16)
        RY_LANE(6, 8)
        RY_LANE(7, 4)
        RY_LANE(8, 2)
        RY_LANE(9, 1)

        // p-wires j=0,1,2 (p bits 2,1,0): real pair rotations
#pragma unroll
        for (int j = 0; j < 3; ++j) {
            const int pb = 4 >> j;
            const float c = rl[j * 2], s = rl[j * 2 + 1];
            const v2f C = sp2(c), S = sp2(s), nS = sp2(-s);
#pragma unroll
            for (int p0 = 0; p0 < 8; ++p0) {
                if (p0 & pb) continue;
                const int p1 = p0 | pb;
                const v2f a0r = sr[p0], a1r = sr[p1];
                const v2f a0i = si[p0], a1i = si[p1];
                sr[p0] = pkfma(C, a0r, nS * a1r);
                sr[p1] = pkfma(C, a1r,  S * a0r);
                si[p0] = pkfma(C, a0i, nS * a1i);
                si[p1] = pkfma(C, a1i,  S * a0i);
            }
        }

        // e-wire j=3 (intra-v2f): new.x = c*x - s*y ; new.y = s*x + c*y
        {
            const float c = rl[6], s = rl[7];
            const v2f C = sp2(c), Sw = mk2(-s, s);
#pragma unroll
            for (int p = 0; p < 8; ++p) {
                const v2f swr = mk2(sr[p].y, sr[p].x);
                const v2f swi = mk2(si[p].y, si[p].x);
                sr[p] = pkfma(C, sr[p], Sw * swr);
                si[p] = pkfma(C, si[p], Sw * swi);
            }
        }

        // fused diagonal D_{L+1} (CZ * RZ(omega_L) * RZ(x) * RZ(phi_{L+1}))
        if (L < 3) {
            BUILD_D(L)
#pragma unroll
            for (int p = 0; p < 8; ++p) {
                const v2f tr = pkfma(sr[p], dr[p], -(si[p] * di[p]));
                si[p] = pkfma(sr[p], di[p], si[p] * dr[p]);
                sr[p] = tr;
            }
        }
    }
#undef RY_LANE
#undef BUILD_D

    // ---- <Z_j> (verified R7 epilogue) ----
    float pe[8], po[8];
#pragma unroll
    for (int p = 0; p < 8; ++p) {
        const v2f pk = pkfma(sr[p], sr[p], si[p] * si[p]);
        pe[p] = pk.x + pk.y;
        po[p] = pk.x - pk.y;
    }
    float tot = 0.f, t0 = 0.f, t1 = 0.f, t2 = 0.f, t3 = 0.f;
#pragma unroll
    for (int p = 0; p < 8; ++p) {
        tot += pe[p];
        t0  += (p & 4) ? -pe[p] : pe[p];   // wire 0 (m bit 3)
        t1  += (p & 2) ? -pe[p] : pe[p];   // wire 1 (m bit 2)
        t2  += (p & 1) ? -pe[p] : pe[p];   // wire 2 (m bit 1)
        t3  += po[p];                      // wire 3 (m bit 0)
    }
    v2f u01 = mk2(t0, t1), u23 = mk2(t2, t3);
    u01 += lxor2<1>(u01);  u23 += lxor2<1>(u23);
    u01 += lxor2<2>(u01);  u23 += lxor2<2>(u23);
    u01 += lxor2<4>(u01);  u23 += lxor2<4>(u23);
    u01 += lxor2<8>(u01);  u23 += lxor2<8>(u23);
    u01 += lxor2<16>(u01); u23 += lxor2<16>(u23);
    u01 += lxor2<32>(u01); u23 += lxor2<32>(u23);

    float Sa = tot, T, D0, D1, D2, D3, D4, D5;
    T = lxor<1>(Sa);  D0 = Sa - T; Sa += T;
    T = lxor<2>(Sa);  D1 = Sa - T; Sa += T;
    T = lxor<4>(Sa);  D2 = Sa - T; Sa += T;
    T = lxor<8>(Sa);  D3 = Sa - T; Sa += T;
    T = lxor<16>(Sa); D4 = Sa - T; Sa += T;
    T = lxor<32>(Sa); D5 = Sa - T;
    D0 += lxor<2>(D0); D0 += lxor<4>(D0); D0 += lxor<8>(D0); D0 += lxor<16>(D0); D0 += lxor<32>(D0);
    D1 += lxor<4>(D1); D1 += lxor<8>(D1); D1 += lxor<16>(D1); D1 += lxor<32>(D1);
    D2 += lxor<8>(D2); D2 += lxor<16>(D2); D2 += lxor<32>(D2);
    D3 += lxor<16>(D3); D3 += lxor<32>(D3);
    D4 += lxor<32>(D4);

    if (lane == 0) {
        float* o = out + b * NQ;
        o[0] = u01.x; o[1] = u01.y; o[2] = u23.x; o[3] = u23.y;
        o[4] = D5;    o[5] = D4;    o[6] = D3;    o[7] = D2;    o[8] = D1;    o[9] = D0;
    }
}

extern "C" void kernel_launch(void* const* d_in, const int* in_sizes, int n_in,
                              void* d_out, int out_size, void* d_ws, size_t ws_size,
                              hipStream_t stream) {
    const float* x  = (const float*)d_in[0];   // [B,10] f32
    const float* w1 = (const float*)d_in[1];   // [3,1,10,3] f32
    const float* w2 = (const float*)d_in[2];   // [1,10,3] f32
    float* out = (float*)d_out;                // [B,10] f32
    const int B = in_sizes[0] / NQ;            // 2048
    qlayer_kernel<<<B / 4, 256, 0, stream>>>(x, w1, w2, out);
}

// Round 10
// 17.753 us; speedup vs baseline: 1.4804x; 1.0164x over previous
//
#include <hip/hip_runtime.h>
#include <math.h>

#define NQ 10

typedef float v2f __attribute__((ext_vector_type(2)));

static __device__ __forceinline__ v2f mk2(float a, float b) { v2f r; r.x = a; r.y = b; return r; }
static __device__ __forceinline__ v2f sp2(float a)          { v2f r; r.x = a; r.y = a; return r; }
static __device__ __forceinline__ v2f pkfma(v2f a, v2f b, v2f c) { return __builtin_elementwise_fma(a, b, c); }

// xor-mask lane exchange for DPP-reachable masks (VALU pipe) + DS fallbacks
// (only used in the epilogue now).
template<int MSK>
static __device__ __forceinline__ float lxor(float v) {
    if constexpr (MSK == 1) {        // quad_perm [1,0,3,2]
        const int s = __float_as_int(v);
        return __int_as_float(__builtin_amdgcn_update_dpp(s, s, 0xB1, 0xF, 0xF, false));
    } else if constexpr (MSK == 2) { // quad_perm [2,3,0,1]
        const int s = __float_as_int(v);
        return __int_as_float(__builtin_amdgcn_update_dpp(s, s, 0x4E, 0xF, 0xF, false));
    } else if constexpr (MSK == 4) {
        // banks 0,2 (bit2=0) need lane+4 -> row_shl:4 ; banks 1,3 (bit2=1) need lane-4 -> row_shr:4
        const int s = __float_as_int(v);
        int t = __builtin_amdgcn_update_dpp(s, s, 0x104, 0xF, 0x5, false); // row_shl:4 into banks 0,2
        t     = __builtin_amdgcn_update_dpp(t, s, 0x114, 0xF, 0xA, false); // row_shr:4 into banks 1,3
        return __int_as_float(t);
    } else if constexpr (MSK == 8) { // row_ror:8 == xor8 within a 16-lane row
        const int s = __float_as_int(v);
        return __int_as_float(__builtin_amdgcn_update_dpp(s, s, 0x128, 0xF, 0xF, false));
    } else if constexpr (MSK == 16) {
        return __int_as_float(__builtin_amdgcn_ds_swizzle(__float_as_int(v), 0x401F));
    } else {
        return __shfl_xor(v, 32, 64);
    }
}
template<int MSK>
static __device__ __forceinline__ v2f lxor2(v2f v) { return mk2(lxor<MSK>(v.x), lxor<MSK>(v.y)); }

// Dual-destination permlane swaps (gfx950, VALU pipe, both operands modified):
//  v_permlane32_swap_b32 a,b: a.hi(lanes 32-63) <-> b.lo(lanes 0-31)
//  v_permlane16_swap_b32 a,b: a.rows{1,3} <-> b.rows{0,2}   (row = 16 lanes)
#define PLS32(a, b) asm("v_permlane32_swap_b32 %0, %1" : "+v"(a), "+v"(b))
#define PLS16(a, b) asm("v_permlane16_swap_b32 %0, %1" : "+v"(a), "+v"(b))

// One WAVE per batch element (4 per 256-thread block). k = m*64+lane, m = 2p+e.
// Circuit algebraically reduced to:  P0 (real product state = RY0|0..0>)
//   -> D1 -> RY1 -> D2 -> RY2 -> D3 -> RY3 -> |.|^2
// RY is REAL, so sr and si transform identically -> pair (sr[p], si[p]) as the
// two operands of a permlane swap: after swap, u=(sr.lo,si.lo), v=(sr.hi,si.hi),
// gate is t1 = c*u - s*v, t2 = c*v + s*u (uniform signs, no per-lane select),
// and a second swap restores layout: t1=new_sr, t2=new_si. Main loop = 0 DS ops.
__global__ void qlayer_kernel(
    const float* __restrict__ x,    // [B,10]
    const float* __restrict__ w1,   // [3,1,10,3]
    const float* __restrict__ w2,   // [1,10,3]
    float* __restrict__ out)        // [B,10]
{
    __shared__ float ry[4 * 20];   // (c,s)(theta/2) per layer L=0..3, wire j=0..9
    __shared__ float au[3 * 10];   // omega_L[j] + phi_{L+1}[j], L=0..2

    const int t    = threadIdx.x;
    const int lane = t & 63;
    const int w    = t >> 6;
    const int b    = (blockIdx.x << 2) + w;

    if (t < 40) {
        const int L = t / 10, j = t - L * 10;
        const float th = (L < 3) ? w1[L * 30 + j * 3 + 1] : w2[j * 3 + 1];
        float c, s;
        __sincosf(0.5f * th, &s, &c);
        ry[L * 20 + j * 2 + 0] = c;
        ry[L * 20 + j * 2 + 1] = s;
    } else if (t >= 64 && t < 94) {
        const int i = t - 64, L = i / 10, j = i - L * 10;
        au[i] = w1[L * 30 + j * 3 + 2] + ((L < 2) ? w1[(L + 1) * 30 + j * 3] : w2[j * 3]);
    }

    float xv[NQ];
#pragma unroll
    for (int j = 0; j < NQ; ++j) xv[j] = x[b * NQ + j];

    // sign masks for the DPP wires only (lane bits 0..3; bit set -> +s, clear -> -s)
    int msk[4];
#pragma unroll
    for (int p = 0; p < 4; ++p) msk[p] = ((lane >> p) & 1) ? 0 : 0x80000000;

    // CZ-ring sign per m (k = m<<6 | lane)
    float czm[16];
#pragma unroll
    for (int m = 0; m < 16; ++m) {
        const int k  = (m << 6) | lane;
        const int kr = ((k << 1) | (k >> 9)) & 1023;
        czm[m] = (__popc(k & kr) & 1) ? -1.f : 1.f;
    }

    __syncthreads();   // tables ready (only block barrier)

    // D build: d = cz * exp(i*ang(k)), ang(k) = -SA/2 + sum_{bits set} A[wire]
    v2f dr[8], di[8];
#define BUILD_D(IDX)                                                                   \
    {                                                                                  \
        float A[NQ];                                                                   \
        _Pragma("unroll")                                                              \
        for (int j = 0; j < NQ; ++j) A[j] = au[(IDX) * 10 + j] + xv[j];                \
        float SA = 0.f;                                                                \
        _Pragma("unroll")                                                              \
        for (int j = 0; j < NQ; ++j) SA += A[j];                                       \
        float Tl = 0.f;                                                                \
        _Pragma("unroll")                                                              \
        for (int p = 0; p < 6; ++p) Tl += ((lane >> p) & 1) ? A[9 - p] : 0.f;          \
        const float base = -0.5f * SA + Tl;                                            \
        float fr[4], fi[4];                                                            \
        _Pragma("unroll")                                                              \
        for (int q = 0; q < 4; ++q) __sincosf(A[3 - q], &fi[q], &fr[q]);               \
        float dmr[16], dmi[16];                                                        \
        __sincosf(base, &dmi[0], &dmr[0]);                                             \
        _Pragma("unroll")                                                              \
        for (int m = 1; m < 16; ++m) {                                                 \
            const int q  = (m & 1) ? 0 : (m & 2) ? 1 : (m & 4) ? 2 : 3;                \
            const int pm = m & (m - 1);                                                \
            dmr[m] = dmr[pm] * fr[q] - dmi[pm] * fi[q];                                \
            dmi[m] = dmr[pm] * fi[q] + dmi[pm] * fr[q];                                \
        }                                                                              \
        _Pragma("unroll")                                                              \
        for (int p = 0; p < 8; ++p) {                                                  \
            dr[p] = mk2(dmr[2*p] * czm[2*p], dmr[2*p+1] * czm[2*p+1]);                 \
            di[p] = mk2(dmi[2*p] * czm[2*p], dmi[2*p+1] * czm[2*p+1]);                 \
        }                                                                              \
    }

    // ---- initial product state: RY-block 0 applied to |0..0> ----
    float Plo = 1.f;
#pragma unroll
    for (int p = 0; p < 6; ++p) {       // lane bit p <-> wire 9-p
        const float cc = ry[(9 - p) * 2], ss = ry[(9 - p) * 2 + 1];
        Plo *= ((lane >> p) & 1) ? ss : cc;
    }
    float Pm[16];
    {
        const float c0 = ry[0], s0 = ry[1], c1 = ry[2], s1 = ry[3];
        const float c2 = ry[4], s2 = ry[5], c3 = ry[6], s3 = ry[7];
        float P2[2] = {c3, s3};          // m bit0 = wire 3
        float P4[4], P8[8];
#pragma unroll
        for (int m = 0; m < 4; ++m)  P4[m] = ((m >> 1) ? s2 : c2) * P2[m & 1];
#pragma unroll
        for (int m = 0; m < 8; ++m)  P8[m] = ((m >> 2) ? s1 : c1) * P4[m & 3];
#pragma unroll
        for (int m = 0; m < 16; ++m) Pm[m] = ((m >> 3) ? s0 : c0) * P8[m & 7];
    }

    BUILD_D(0)
    v2f sr[8], si[8];
#pragma unroll
    for (int p = 0; p < 8; ++p) {
        const v2f pv = sp2(Plo) * mk2(Pm[2 * p], Pm[2 * p + 1]);
        sr[p] = pv * dr[p];
        si[p] = pv * di[p];
    }

// DPP lane wires (masks 1,2,4,8): per-lane signed coefficient, in-register partner
#define RY_LANE(J, MSK)                                                         \
    {                                                                           \
        const float c = rl[(J) * 2], s = rl[(J) * 2 + 1];                       \
        const float ssg = __int_as_float(__float_as_int(s) ^ msk[9 - (J)]);     \
        const v2f C = sp2(c), S = sp2(ssg);                                     \
        _Pragma("unroll")                                                       \
        for (int p = 0; p < 8; ++p) {                                           \
            const v2f qr = lxor2<MSK>(sr[p]);                                   \
            const v2f qi = lxor2<MSK>(si[p]);                                   \
            sr[p] = pkfma(C, sr[p], S * qr);                                    \
            si[p] = pkfma(C, si[p], S * qi);                                    \
        }                                                                       \
    }

// permlane pair wires (masks 32,16): pair (sr[p], si[p]); swap -> uniform-sign
// gate -> swap back. 4 permlane + 4 pk-ops per p, zero DS, zero sign-selects.
#define RY_PLPAIR(J, PLS)                                                       \
    {                                                                           \
        const float c = rl[(J) * 2], s = rl[(J) * 2 + 1];                       \
        const v2f C = sp2(c), S = sp2(s), nS = sp2(-s);                         \
        _Pragma("unroll")                                                       \
        for (int p = 0; p < 8; ++p) {                                           \
            float ux = sr[p].x, uy = sr[p].y;                                   \
            float vx = si[p].x, vy = si[p].y;                                   \
            PLS(ux, vx); PLS(uy, vy);                                           \
            const v2f u = mk2(ux, uy), v = mk2(vx, vy);                         \
            const v2f t1 = pkfma(C, u, nS * v);                                 \
            const v2f t2 = pkfma(C, v,  S * u);                                 \
            float ax = t1.x, ay = t1.y, bx = t2.x, by = t2.y;                   \
            PLS(ax, bx); PLS(ay, by);                                           \
            sr[p] = mk2(ax, ay); si[p] = mk2(bx, by);                           \
        }                                                                       \
    }

#pragma unroll 1
    for (int L = 1; L <= 3; ++L) {
        const float* rl = ry + L * 20;

        RY_PLPAIR(4, PLS32)   // lane bit 5
        RY_PLPAIR(5, PLS16)   // lane bit 4
        RY_LANE(6, 8)
        RY_LANE(7, 4)
        RY_LANE(8, 2)
        RY_LANE(9, 1)

        // p-wires j=0,1,2 (p bits 2,1,0): real pair rotations
#pragma unroll
        for (int j = 0; j < 3; ++j) {
            const int pb = 4 >> j;
            const float c = rl[j * 2], s = rl[j * 2 + 1];
            const v2f C = sp2(c), S = sp2(s), nS = sp2(-s);
#pragma unroll
            for (int p0 = 0; p0 < 8; ++p0) {
                if (p0 & pb) continue;
                const int p1 = p0 | pb;
                const v2f a0r = sr[p0], a1r = sr[p1];
                const v2f a0i = si[p0], a1i = si[p1];
                sr[p0] = pkfma(C, a0r, nS * a1r);
                sr[p1] = pkfma(C, a1r,  S * a0r);
                si[p0] = pkfma(C, a0i, nS * a1i);
                si[p1] = pkfma(C, a1i,  S * a0i);
            }
        }

        // e-wire j=3 (intra-v2f): new.x = c*x - s*y ; new.y = s*x + c*y
        {
            const float c = rl[6], s = rl[7];
            const v2f C = sp2(c), Sw = mk2(-s, s);
#pragma unroll
            for (int p = 0; p < 8; ++p) {
                const v2f swr = mk2(sr[p].y, sr[p].x);
                const v2f swi = mk2(si[p].y, si[p].x);
                sr[p] = pkfma(C, sr[p], Sw * swr);
                si[p] = pkfma(C, si[p], Sw * swi);
            }
        }

        // fused diagonal D_{L+1} (CZ * RZ(omega_L) * RZ(x) * RZ(phi_{L+1}))
        if (L < 3) {
            BUILD_D(L)
#pragma unroll
            for (int p = 0; p < 8; ++p) {
                const v2f tr = pkfma(sr[p], dr[p], -(si[p] * di[p]));
                si[p] = pkfma(sr[p], di[p], si[p] * dr[p]);
                sr[p] = tr;
            }
        }
    }
#undef RY_LANE
#undef RY_PLPAIR
#undef BUILD_D

    // ---- <Z_j> (verified R7 epilogue) ----
    float pe[8], po[8];
#pragma unroll
    for (int p = 0; p < 8; ++p) {
        const v2f pk = pkfma(sr[p], sr[p], si[p] * si[p]);
        pe[p] = pk.x + pk.y;
        po[p] = pk.x - pk.y;
    }
    float tot = 0.f, t0 = 0.f, t1 = 0.f, t2 = 0.f, t3 = 0.f;
#pragma unroll
    for (int p = 0; p < 8; ++p) {
        tot += pe[p];
        t0  += (p & 4) ? -pe[p] : pe[p];   // wire 0 (m bit 3)
        t1  += (p & 2) ? -pe[p] : pe[p];   // wire 1 (m bit 2)
        t2  += (p & 1) ? -pe[p] : pe[p];   // wire 2 (m bit 1)
        t3  += po[p];                      // wire 3 (m bit 0)
    }
    v2f u01 = mk2(t0, t1), u23 = mk2(t2, t3);
    u01 += lxor2<1>(u01);  u23 += lxor2<1>(u23);
    u01 += lxor2<2>(u01);  u23 += lxor2<2>(u23);
    u01 += lxor2<4>(u01);  u23 += lxor2<4>(u23);
    u01 += lxor2<8>(u01);  u23 += lxor2<8>(u23);
    u01 += lxor2<16>(u01); u23 += lxor2<16>(u23);
    u01 += lxor2<32>(u01); u23 += lxor2<32>(u23);

    float Sa = tot, T, D0, D1, D2, D3, D4, D5;
    T = lxor<1>(Sa);  D0 = Sa - T; Sa += T;
    T = lxor<2>(Sa);  D1 = Sa - T; Sa += T;
    T = lxor<4>(Sa);  D2 = Sa - T; Sa += T;
    T = lxor<8>(Sa);  D3 = Sa - T; Sa += T;
    T = lxor<16>(Sa); D4 = Sa - T; Sa += T;
    T = lxor<32>(Sa); D5 = Sa - T;
    D0 += lxor<2>(D0); D0 += lxor<4>(D0); D0 += lxor<8>(D0); D0 += lxor<16>(D0); D0 += lxor<32>(D0);
    D1 += lxor<4>(D1); D1 += lxor<8>(D1); D1 += lxor<16>(D1); D1 += lxor<32>(D1);
    D2 += lxor<8>(D2); D2 += lxor<16>(D2); D2 += lxor<32>(D2);
    D3 += lxor<16>(D3); D3 += lxor<32>(D3);
    D4 += lxor<32>(D4);

    if (lane == 0) {
        float* o = out + b * NQ;
        o[0] = u01.x; o[1] = u01.y; o[2] = u23.x; o[3] = u23.y;
        o[4] = D5;    o[5] = D4;    o[6] = D3;    o[7] = D2;    o[8] = D1;    o[9] = D0;
    }
}

extern "C" void kernel_launch(void* const* d_in, const int* in_sizes, int n_in,
                              void* d_out, int out_size, void* d_ws, size_t ws_size,
                              hipStream_t stream) {
    const float* x  = (const float*)d_in[0];   // [B,10] f32
    const float* w1 = (const float*)d_in[1];   // [3,1,10,3] f32
    const float* w2 = (const float*)d_in[2];   // [1,10,3] f32
    float* out = (float*)d_out;                // [B,10] f32
    const int B = in_sizes[0] / NQ;            // 2048
    qlayer_kernel<<<B / 4, 256, 0, stream>>>(x, w1, w2, out);
}